// Round 9
// baseline (222.246 us; speedup 1.0000x reference)
//
#include <hip/hip_runtime.h>

// Gridding: B batches of N float3 points -> per-batch 64^3 grid of trilinear
// scatter weights.
//
// R13: R12 matched its model (105.5 us; ledger: atomics 177K cyc/CU floor +
// ~25K queue/misc + ~50K stall). Binning re-derived honestly: K2 repeats the
// same 177K atomic work, K1 adds ~30us + imbalance -> ~115us, WORSE — the
// redundant scan is free under the DS-bound phase. So attack the stall and
// queue terms inside R12's proven one-round shape:
//  - Queue entry = R10-verified packed u64 (3x21-bit fixed point, s6.15:
//    q = c*2^20 + 2^20; decode q*2^-15 - 32 exact): push = ONE ds_write_b64
//    (was b64+b32). Pack VALU (~10/push) rides the 41% VALU headroom.
//  - QCAP=192, drain TWO entries/lane at qn>=128: halves drain events and
//    pipelines the two ds_read_b64 (the reads were stalling ~300cyc behind
//    the DS pipe's atomic backlog). 8B entries keep queue at 24KB -> LDS
//    total 155648 B — exactly R12's proven footprint, TPB=1024 unchanged.
//  - b128 grid init (ulonglong2).
//  - Scatter body / slim test / decode identical to R12; pack path identical
//    to R10 (harness-verified absmax 0.03125). Floor-flip hazard handled by
//    heavy's rel-range insurance return (dropped writes weigh < 2^-15 -> 0).
// Ledger: DS ~199K + stall ~25K ~ 225K cyc ~ 94 us predicted.

#define GS    64
#define G2    (GS * GS)          // 4096
#define G3    (GS * GS * GS)     // 262144
#define SHALF 32                 // scale (half-extent)
#define TH    8                  // planes per slab
#define NSLAB (GS / TH)          // 8
#define TPB   1024
#define NWG   (TH * 1024)        // u64 words per grid (8 planes x 1024 tiles)
#define NWAVE (TPB / 64)         // 16
#define QCAP  192                // per-wave queue (qn<128 invariant + push<=64)

#define QSF   1024.0f            // weight quantization scale (2^10)
#define QDEC  (1.0f / 1024.0f)
#define PKS   1048576.0f         // 2^20: pack scale/offset
#define UPK   (1.0f / 32768.0f)  // 2^-15: unpack scale

typedef unsigned long long ull;

__device__ __forceinline__ ull pack4(unsigned q00, unsigned q01,
                                     unsigned q10, unsigned q11) {
    // field f = dy*2+dz at bits [16f, 16f+16)
    return (ull)q00 | ((ull)q01 << 16) | ((ull)q10 << 32) | ((ull)q11 << 48);
}

// Heavy body: unpack coords (exact multiples of 2^-15), weights, quantize,
// dual-grid packed LDS atomics (R8/R12 scatter verbatim).
__device__ __forceinline__ void heavy(ull e, int k,
                                      ull* __restrict__ A64,
                                      ull* __restrict__ B64) {
    float x = (float)(int)(unsigned)(e & 0x1FFFFF)         * UPK - 32.0f;
    float y = (float)(int)(unsigned)((e >> 21) & 0x1FFFFF) * UPK - 32.0f;
    float z = (float)(int)(unsigned)((e >> 42) & 0x1FFFFF) * UPK - 32.0f;

    float lx = floorf(x), ly = floorf(y), lz = floorf(z);
    int ix = min(max((int)lx + SHALF, 0), GS - 2);
    int iy = min(max((int)ly + SHALF, 0), GS - 2);
    int iz = min(max((int)lz + SHALF, 0), GS - 2);
    int rel = ix - TH * k;
    // pack can flip floor at integer boundaries (rel -> -2 or 8); those
    // writes carry weight < 2^-15 -> drop (R10-verified).
    if ((unsigned)(rel + 1) > TH) return;

    float fx = x - lx, fy = y - ly, fz = z - lz;
    float wx0 = (1.0f - fx) * ((rel >= 0)      ? 1.0f : 0.0f);
    float wx1 = fx          * ((rel <= TH - 2) ? 1.0f : 0.0f);
    int plo = max(rel, 0);
    int phi = min(rel + 1, TH - 1);

    float wy0 = 1.0f - fy, wy1 = fy;
    float wz0 = 1.0f - fz, wz1 = fz;
    float a00 = wx0 * wy0, a01 = wx0 * wy1;
    float b00 = wx1 * wy0, b01 = wx1 * wy1;

    // quantize (round-half-up; all weights >= 0). q[plane][dy][dz]
    unsigned qa00z0 = (unsigned)(a00 * wz0 * QSF + 0.5f);
    unsigned qa00z1 = (unsigned)(a00 * wz1 * QSF + 0.5f);
    unsigned qa01z0 = (unsigned)(a01 * wz0 * QSF + 0.5f);
    unsigned qa01z1 = (unsigned)(a01 * wz1 * QSF + 0.5f);
    unsigned qb00z0 = (unsigned)(b00 * wz0 * QSF + 0.5f);
    unsigned qb00z1 = (unsigned)(b00 * wz1 * QSF + 0.5f);
    unsigned qb01z0 = (unsigned)(b01 * wz0 * QSF + 0.5f);
    unsigned qb01z1 = (unsigned)(b01 * wz1 * QSF + 0.5f);

    const int t0  = (iy >> 1) * 32 + (iz >> 1);  // tile word within plane
    const int wlo = plo * 1024 + t0;
    const int whi = phi * 1024 + t0;
    const int dy = iy & 1, dz = iz & 1;

    if (dy == dz) {
        // whole 2x2 quad lives in one tile of A (even,even) or B (odd,odd)
        ull* g = dy ? B64 : A64;
        ull va = pack4(qa00z0, qa00z1, qa01z0, qa01z1);
        ull vb = pack4(qb00z0, qb00z1, qb01z0, qb01z1);
        if (va) atomicAdd(&g[wlo], va);
        if (vb) atomicAdd(&g[whi], vb);
    } else if (dz) {
        // iy even, iz odd: z-straddle in A -> tiles t0 (fields 1,3), t0+1 (0,2)
        ull va1 = ((ull)qa00z0 << 16) | ((ull)qa01z0 << 48);
        ull va2 = ((ull)qa00z1)       | ((ull)qa01z1 << 32);
        ull vb1 = ((ull)qb00z0 << 16) | ((ull)qb01z0 << 48);
        ull vb2 = ((ull)qb00z1)       | ((ull)qb01z1 << 32);
        if (va1) atomicAdd(&A64[wlo],     va1);
        if (va2) atomicAdd(&A64[wlo + 1], va2);
        if (vb1) atomicAdd(&A64[whi],     vb1);
        if (vb2) atomicAdd(&A64[whi + 1], vb2);
    } else {
        // iy odd, iz even: y-straddle in A -> tiles t0 (fields 2,3), t0+32 (0,1)
        ull va1 = ((ull)qa00z0 << 32) | ((ull)qa00z1 << 48);
        ull va2 = ((ull)qa01z0)       | ((ull)qa01z1 << 16);
        ull vb1 = ((ull)qb00z0 << 32) | ((ull)qb00z1 << 48);
        ull vb2 = ((ull)qb01z0)       | ((ull)qb01z1 << 16);
        if (va1) atomicAdd(&A64[wlo],      va1);
        if (va2) atomicAdd(&A64[wlo + 32], va2);
        if (vb1) atomicAdd(&A64[whi],      vb1);
        if (vb2) atomicAdd(&A64[whi + 32], vb2);
    }
}

// slim test + ballot-compacted packed push; 2-deep drain at qn>=128
__device__ __forceinline__ void push_pt(float px, float py, float pz,
                                        float lo, float hi, int k, int lane,
                                        ull* __restrict__ q, int& qn,
                                        ull* __restrict__ A64,
                                        ull* __restrict__ B64) {
    // membership: px in [lo, hi)  <=>  ix(clamped) in [8k-1, 8k+7]
    bool pass = (px >= lo) & (px < hi) & ((px + py + pz) != 0.0f);
    ull m = __ballot(pass);
    if (pass) {
        // pack coord c as (c*32 + 32)*2^15 = c*2^20 + 2^20, trunc to 21 bits
        unsigned qx = (unsigned)fmaf(px, PKS, PKS);
        unsigned qy = (unsigned)fmaf(py, PKS, PKS);
        unsigned qz = (unsigned)fmaf(pz, PKS, PKS);
        q[qn + (int)__popcll(m & ((1ull << lane) - 1))] =
            (ull)qx | ((ull)qy << 21) | ((ull)qz << 42);
    }
    qn += (int)__popcll(m);          // wave-uniform
    if (qn >= 128) {                 // wave-uniform 2-deep drain
        qn -= 128;
        ull e0 = q[qn + lane];       // both reads issue before first use
        ull e1 = q[qn + 64 + lane];
        heavy(e0, k, A64, B64);
        heavy(e1, k, A64, B64);
    }
}

__global__ __launch_bounds__(TPB, 1) void gridding_u16_kernel(
    const float* __restrict__ pt, float* __restrict__ out, int N) {
    alignas(16) __shared__ ull A64[NWG];    // 64 KB: even-aligned 2x2 tiles
    alignas(16) __shared__ ull B64[NWG];    // 64 KB: (1,1)-offset tiles
    __shared__ ull qe[NWAVE * QCAP];        // 24 KB: per-wave packed queues

    const int b    = blockIdx.x;   // batch (b%8 XCD affinity)
    const int k    = blockIdx.y;   // slab (8 planes)
    const int tid  = threadIdx.x;
    const int wid  = tid >> 6;
    const int lane = tid & 63;

    {   // b128 init
        ulonglong2* a2 = (ulonglong2*)A64;
        ulonglong2* b2 = (ulonglong2*)B64;
        const ulonglong2 z2 = {0ull, 0ull};
        for (int t = tid; t < NWG / 2; t += TPB) { a2[t] = z2; b2[t] = z2; }
    }
    __syncthreads();

    // slab bounds in raw-point units (integer/32, exact in fp32)
    const float lo = (k == 0)         ? -1e30f
                                      : (float)(TH * k - 33) * (1.0f / 32.0f);
    const float hi = (k == NSLAB - 1) ? 1e30f
                                      : (float)(TH * k - 24) * (1.0f / 32.0f);

    const float4* p4 = (const float4*)(pt + (size_t)b * N * 3);
    ull* q  = qe + wid * QCAP;
    int  qn = 0;

    const int nq    = N >> 2;          // 4-point quads
    const int niter = nq / TPB;        // exact (launcher guards N%(4*TPB)==0)

    for (int it = 0; it < niter; ++it) {
        int qd = it * TPB + tid;
        float4 A = p4[3 * qd + 0], Bv = p4[3 * qd + 1], C = p4[3 * qd + 2];
        push_pt(A.x,  A.y,  A.z,  lo, hi, k, lane, q, qn, A64, B64);
        push_pt(A.w,  Bv.x, Bv.y, lo, hi, k, lane, q, qn, A64, B64);
        push_pt(Bv.z, Bv.w, C.x,  lo, hi, k, lane, q, qn, A64, B64);
        push_pt(C.y,  C.z,  C.w,  lo, hi, k, lane, q, qn, A64, B64);
    }
    // tail drain (qn in [0,127], wave-uniform)
    if (qn >= 64) {
        qn -= 64;
        heavy(q[qn + lane], k, A64, B64);
    }
    if (lane < qn) heavy(q[lane], k, A64, B64);
    __syncthreads();

    // decode: cell (pl, iy, iz) = A[tile(iy,iz)] + B[tile(iy-1,iz-1)]
    const unsigned short* a16 = (const unsigned short*)A64;
    const unsigned short* b16 = (const unsigned short*)B64;
    float* ob = out + (size_t)b * G3 + (size_t)(TH * k) * G2;
    for (int t = tid; t < TH * G2; t += TPB) {
        int pl = t >> 12;
        int cell = t & 4095;
        int iy = cell >> 6, iz = cell & 63;
        unsigned v = a16[(pl << 12) +
                         (((iy >> 1) * 32 + (iz >> 1)) << 2) +
                         ((iy & 1) << 1) + (iz & 1)];
        if (iy > 0 && iz > 0) {
            v += b16[(pl << 12) +
                     ((((iy - 1) >> 1) * 32 + ((iz - 1) >> 1)) << 2) +
                     (((iy - 1) & 1) << 1) + ((iz - 1) & 1)];
        }
        ob[t] = (float)v * QDEC;
    }
}

// ---- fallback (general shapes): R1 atomic kernel ----
__global__ void gridding_atomic_kernel(const float* __restrict__ pt,
                                       float* __restrict__ out, int P, int N) {
    int i = blockIdx.x * blockDim.x + threadIdx.x;
    if (i >= P) return;
    int b = i / N;
    float x = pt[3 * i + 0] * (float)SHALF;
    float y = pt[3 * i + 1] * (float)SHALF;
    float z = pt[3 * i + 2] * (float)SHALF;
    const float m = ((x + y + z) != 0.0f) ? 1.0f : 0.0f;
    float lx = floorf(x), ly = floorf(y), lz = floorf(z);
    float fx = x - lx, fy = y - ly, fz = z - lz;
    int ix = min(max((int)lx + SHALF, 0), GS - 2);
    int iy = min(max((int)ly + SHALF, 0), GS - 2);
    int iz = min(max((int)lz + SHALF, 0), GS - 2);
    float* base = out + (size_t)b * G3 + ((ix * GS + iy) * GS + iz);
    float wx0 = (1.0f - fx) * m, wx1 = fx * m;
    float w00 = wx0 * (1.0f - fy), w01 = wx0 * fy;
    float w10 = wx1 * (1.0f - fy), w11 = wx1 * fy;
    atomicAdd(base,               w00 * (1.0f - fz));
    atomicAdd(base + 1,           w00 * fz);
    atomicAdd(base + GS,          w01 * (1.0f - fz));
    atomicAdd(base + GS + 1,      w01 * fz);
    atomicAdd(base + G2,          w10 * (1.0f - fz));
    atomicAdd(base + G2 + 1,      w10 * fz);
    atomicAdd(base + G2 + GS,     w11 * (1.0f - fz));
    atomicAdd(base + G2 + GS + 1, w11 * fz);
}

extern "C" void kernel_launch(void* const* d_in, const int* in_sizes, int n_in,
                              void* d_out, int out_size, void* d_ws, size_t ws_size,
                              hipStream_t stream) {
    const float* pt  = (const float*)d_in[0];
    float*       out = (float*)d_out;

    const int P = in_sizes[0] / 3;       // total points (B*N)
    const int B = out_size / G3;         // 32
    const int N = (B > 0) ? P / B : 0;   // 262144

    const bool fast = (B > 0) && (out_size == B * G3) && (P == B * N) &&
                      (N % (4 * TPB) == 0);

    if (fast) {
        dim3 g(B, NSLAB);                // 256 wgs = 1/CU, one round
        gridding_u16_kernel<<<g, TPB, 0, stream>>>(pt, out, N);
    } else {
        hipMemsetAsync(d_out, 0, (size_t)out_size * sizeof(float), stream);
        gridding_atomic_kernel<<<(P + 255) / 256, 256, 0, stream>>>(pt, out, P, N);
    }
}

// Round 10
// 215.116 us; speedup vs baseline: 1.0331x; 1.0331x over previous
//
#include <hip/hip_runtime.h>

// Gridding: B batches of N float3 points -> per-batch 64^3 grid of trilinear
// scatter weights.
//
// R14: R13 post-mortem: pack VALU (+46K cyc/SIMD, reproducing R10) is ~73%
// visible in runtime — pipes overlap only ~27% (runtime ~ 0.73*(DS+VALU)
// fits R10/R12/R13). R12 (105.5us) = atomics 177K (structural floor:
// 4-parity's 2/pt needs 2MB/batch -> 2 rounds -> verified -45us in R11)
// + VALU 147K + ~50K stall. Last unattacked stall source: the drain's
// ds_read pops the stack TOP = entries just written by the SAME push ->
// LDS same-address RAW hazard (lgkmcnt wait on own ds_write) + read
// latency, serial at each of ~36 drains/wave.
// Fix (single change vs R12): SOFTWARE-PIPELINED DRAIN — at qn>=64, issue
// the 64 reads into registers (float2+float, 3 VGPR) and set a wave-uniform
// pending flag; execute heavy() for them at the NEXT drain trigger (~6-7
// push-iters ~ 250+cyc of scan in between hides hazard + latency). Atomic
// scatters commute -> write-set identical to R12 -> bit-identical output.
// Predicted: 95-101us dispatch; VALUBusy 60-64%; absmax exactly 0.03125.
// LDS: 2x64K grids + 16K qxy + 8K qz = 155648 B (R12-proven), 1 blk/CU.

#define GS    64
#define G2    (GS * GS)          // 4096
#define G3    (GS * GS * GS)     // 262144
#define SHALF 32                 // scale (half-extent)
#define TH    8                  // planes per slab
#define NSLAB (GS / TH)          // 8
#define TPB   1024
#define NWG   (TH * 1024)        // u64 words per grid (8 planes x 1024 tiles)
#define NWAVE (TPB / 64)         // 16
#define QCAP  128                // per-wave queue capacity (qn<64 + push<=64)

#define QSF   1024.0f            // weight quantization scale (2^10)
#define QDEC  (1.0f / 1024.0f)

typedef unsigned long long ull;

__device__ __forceinline__ ull pack4(unsigned q00, unsigned q01,
                                     unsigned q10, unsigned q11) {
    // field f = dy*2+dz at bits [16f, 16f+16)
    return (ull)q00 | ((ull)q01 << 16) | ((ull)q10 << 32) | ((ull)q11 << 48);
}

// R8/R12 heavy body (verbatim scatter): weights, quantize, dual-grid packed
// LDS atomics. Takes RAW point coords; precondition: passed slim test.
__device__ __forceinline__ void heavy(float px, float py, float pz, int k,
                                      ull* __restrict__ A64,
                                      ull* __restrict__ B64) {
    float x = px * (float)SHALF;
    float y = py * (float)SHALF;
    float z = pz * (float)SHALF;

    float lx = floorf(x), ly = floorf(y), lz = floorf(z);
    int ix = min(max((int)lx + SHALF, 0), GS - 2);
    int iy = min(max((int)ly + SHALF, 0), GS - 2);
    int iz = min(max((int)lz + SHALF, 0), GS - 2);
    int rel = ix - TH * k;
    if ((unsigned)(rel + 1) > TH) return;    // insurance; proven never true

    float fx = x - lx, fy = y - ly, fz = z - lz;
    float wx0 = (1.0f - fx) * ((rel >= 0)      ? 1.0f : 0.0f);
    float wx1 = fx          * ((rel <= TH - 2) ? 1.0f : 0.0f);
    int plo = max(rel, 0);
    int phi = min(rel + 1, TH - 1);

    float wy0 = 1.0f - fy, wy1 = fy;
    float wz0 = 1.0f - fz, wz1 = fz;
    float a00 = wx0 * wy0, a01 = wx0 * wy1;
    float b00 = wx1 * wy0, b01 = wx1 * wy1;

    // quantize (round-half-up; all weights >= 0). q[plane][dy][dz]
    unsigned qa00z0 = (unsigned)(a00 * wz0 * QSF + 0.5f);
    unsigned qa00z1 = (unsigned)(a00 * wz1 * QSF + 0.5f);
    unsigned qa01z0 = (unsigned)(a01 * wz0 * QSF + 0.5f);
    unsigned qa01z1 = (unsigned)(a01 * wz1 * QSF + 0.5f);
    unsigned qb00z0 = (unsigned)(b00 * wz0 * QSF + 0.5f);
    unsigned qb00z1 = (unsigned)(b00 * wz1 * QSF + 0.5f);
    unsigned qb01z0 = (unsigned)(b01 * wz0 * QSF + 0.5f);
    unsigned qb01z1 = (unsigned)(b01 * wz1 * QSF + 0.5f);

    const int t0  = (iy >> 1) * 32 + (iz >> 1);  // tile word within plane
    const int wlo = plo * 1024 + t0;
    const int whi = phi * 1024 + t0;
    const int dy = iy & 1, dz = iz & 1;

    if (dy == dz) {
        // whole 2x2 quad lives in one tile of A (even,even) or B (odd,odd)
        ull* g = dy ? B64 : A64;
        ull va = pack4(qa00z0, qa00z1, qa01z0, qa01z1);
        ull vb = pack4(qb00z0, qb00z1, qb01z0, qb01z1);
        if (va) atomicAdd(&g[wlo], va);
        if (vb) atomicAdd(&g[whi], vb);
    } else if (dz) {
        // iy even, iz odd: z-straddle in A -> tiles t0 (fields 1,3), t0+1 (0,2)
        ull va1 = ((ull)qa00z0 << 16) | ((ull)qa01z0 << 48);
        ull va2 = ((ull)qa00z1)       | ((ull)qa01z1 << 32);
        ull vb1 = ((ull)qb00z0 << 16) | ((ull)qb01z0 << 48);
        ull vb2 = ((ull)qb00z1)       | ((ull)qb01z1 << 32);
        if (va1) atomicAdd(&A64[wlo],     va1);
        if (va2) atomicAdd(&A64[wlo + 1], va2);
        if (vb1) atomicAdd(&A64[whi],     vb1);
        if (vb2) atomicAdd(&A64[whi + 1], vb2);
    } else {
        // iy odd, iz even: y-straddle in A -> tiles t0 (fields 2,3), t0+32 (0,1)
        ull va1 = ((ull)qa00z0 << 32) | ((ull)qa00z1 << 48);
        ull va2 = ((ull)qa01z0)       | ((ull)qa01z1 << 16);
        ull vb1 = ((ull)qb00z0 << 32) | ((ull)qb00z1 << 48);
        ull vb2 = ((ull)qb01z0)       | ((ull)qb01z1 << 16);
        if (va1) atomicAdd(&A64[wlo],      va1);
        if (va2) atomicAdd(&A64[wlo + 32], va2);
        if (vb1) atomicAdd(&A64[whi],      vb1);
        if (vb2) atomicAdd(&A64[whi + 32], vb2);
    }
}

// slim test + ballot-compacted raw push; PIPELINED drain: at qn>=64 issue
// reads into regs, execute the PREVIOUS batch's heavy (hazard+latency hidden
// under ~6-7 intervening push-iterations of scan work).
__device__ __forceinline__ void push_pt(float px, float py, float pz,
                                        float lo, float hi, int k, int lane,
                                        float2* __restrict__ qxy,
                                        float* __restrict__ qz, int& qn,
                                        bool& pending, float2& sxy, float& sz,
                                        ull* __restrict__ A64,
                                        ull* __restrict__ B64) {
    // membership: px in [lo, hi)  <=>  ix(clamped) in [8k-1, 8k+7]
    bool pass = (px >= lo) & (px < hi) & ((px + py + pz) != 0.0f);
    ull m = __ballot(pass);
    if (pass) {
        int idx = qn + (int)__popcll(m & ((1ull << lane) - 1));
        qxy[idx] = make_float2(px, py);   // aligned -> ds_write_b64
        qz[idx]  = pz;                    // ds_write_b32
    }
    qn += (int)__popcll(m);          // wave-uniform
    if (qn >= 64) {                  // wave-uniform branch (SGPR compare)
        qn -= 64;
        float2 nxy = qxy[qn + lane]; // issue reads of the just-filled 64
        float  nz  = qz[qn + lane];
        if (pending) heavy(sxy.x, sxy.y, sz, k, A64, B64);  // previous batch
        sxy = nxy; sz = nz;          // becomes pending; consumed next trigger
        pending = true;
    }
}

__global__ __launch_bounds__(TPB, 1) void gridding_u16_kernel(
    const float* __restrict__ pt, float* __restrict__ out, int N) {
    alignas(16) __shared__ ull A64[NWG];    // 64 KB: even-aligned 2x2 tiles
    alignas(16) __shared__ ull B64[NWG];    // 64 KB: (1,1)-offset tiles
    __shared__ float2 qxy[NWAVE * QCAP];    // 16 KB: per-wave (x,y) queues
    __shared__ float  qz [NWAVE * QCAP];    //  8 KB: per-wave z queues

    const int b    = blockIdx.x;   // batch (b%8 XCD affinity)
    const int k    = blockIdx.y;   // slab (8 planes)
    const int tid  = threadIdx.x;
    const int wid  = tid >> 6;
    const int lane = tid & 63;

    {   // b128 init
        ulonglong2* a2 = (ulonglong2*)A64;
        ulonglong2* b2 = (ulonglong2*)B64;
        const ulonglong2 z2 = {0ull, 0ull};
        for (int t = tid; t < NWG / 2; t += TPB) { a2[t] = z2; b2[t] = z2; }
    }
    __syncthreads();

    // slab bounds in raw-point units (integer/32, exact in fp32)
    const float lo = (k == 0)         ? -1e30f
                                      : (float)(TH * k - 33) * (1.0f / 32.0f);
    const float hi = (k == NSLAB - 1) ? 1e30f
                                      : (float)(TH * k - 24) * (1.0f / 32.0f);

    const float4* p4 = (const float4*)(pt + (size_t)b * N * 3);
    float2* qxyw = qxy + wid * QCAP;
    float*  qzw  = qz  + wid * QCAP;
    int     qn   = 0;

    bool   pending = false;
    float2 sxy     = make_float2(0.0f, 0.0f);
    float  sz      = 0.0f;

    const int nq    = N >> 2;          // 4-point quads
    const int niter = nq / TPB;        // exact (launcher guards N%(4*TPB)==0)

    for (int it = 0; it < niter; ++it) {
        int qd = it * TPB + tid;
        float4 A = p4[3 * qd + 0], Bv = p4[3 * qd + 1], C = p4[3 * qd + 2];
        push_pt(A.x,  A.y,  A.z,  lo, hi, k, lane, qxyw, qzw, qn,
                pending, sxy, sz, A64, B64);
        push_pt(A.w,  Bv.x, Bv.y, lo, hi, k, lane, qxyw, qzw, qn,
                pending, sxy, sz, A64, B64);
        push_pt(Bv.z, Bv.w, C.x,  lo, hi, k, lane, qxyw, qzw, qn,
                pending, sxy, sz, A64, B64);
        push_pt(C.y,  C.z,  C.w,  lo, hi, k, lane, qxyw, qzw, qn,
                pending, sxy, sz, A64, B64);
    }
    // flush pipeline: pending register batch, then leftover queue [0, qn)
    if (pending) heavy(sxy.x, sxy.y, sz, k, A64, B64);
    if (lane < qn) {
        float2 xy = qxyw[lane];
        float  z  = qzw[lane];
        heavy(xy.x, xy.y, z, k, A64, B64);
    }
    __syncthreads();

    // decode: cell (pl, iy, iz) = A[tile(iy,iz)] + B[tile(iy-1,iz-1)]
    const unsigned short* a16 = (const unsigned short*)A64;
    const unsigned short* b16 = (const unsigned short*)B64;
    float* ob = out + (size_t)b * G3 + (size_t)(TH * k) * G2;
    for (int t = tid; t < TH * G2; t += TPB) {
        int pl = t >> 12;
        int cell = t & 4095;
        int iy = cell >> 6, iz = cell & 63;
        unsigned v = a16[(pl << 12) +
                         (((iy >> 1) * 32 + (iz >> 1)) << 2) +
                         ((iy & 1) << 1) + (iz & 1)];
        if (iy > 0 && iz > 0) {
            v += b16[(pl << 12) +
                     ((((iy - 1) >> 1) * 32 + ((iz - 1) >> 1)) << 2) +
                     (((iy - 1) & 1) << 1) + ((iz - 1) & 1)];
        }
        ob[t] = (float)v * QDEC;
    }
}

// ---- fallback (general shapes): R1 atomic kernel ----
__global__ void gridding_atomic_kernel(const float* __restrict__ pt,
                                       float* __restrict__ out, int P, int N) {
    int i = blockIdx.x * blockDim.x + threadIdx.x;
    if (i >= P) return;
    int b = i / N;
    float x = pt[3 * i + 0] * (float)SHALF;
    float y = pt[3 * i + 1] * (float)SHALF;
    float z = pt[3 * i + 2] * (float)SHALF;
    const float m = ((x + y + z) != 0.0f) ? 1.0f : 0.0f;
    float lx = floorf(x), ly = floorf(y), lz = floorf(z);
    float fx = x - lx, fy = y - ly, fz = z - lz;
    int ix = min(max((int)lx + SHALF, 0), GS - 2);
    int iy = min(max((int)ly + SHALF, 0), GS - 2);
    int iz = min(max((int)lz + SHALF, 0), GS - 2);
    float* base = out + (size_t)b * G3 + ((ix * GS + iy) * GS + iz);
    float wx0 = (1.0f - fx) * m, wx1 = fx * m;
    float w00 = wx0 * (1.0f - fy), w01 = wx0 * fy;
    float w10 = wx1 * (1.0f - fy), w11 = wx1 * fy;
    atomicAdd(base,               w00 * (1.0f - fz));
    atomicAdd(base + 1,           w00 * fz);
    atomicAdd(base + GS,          w01 * (1.0f - fz));
    atomicAdd(base + GS + 1,      w01 * fz);
    atomicAdd(base + G2,          w10 * (1.0f - fz));
    atomicAdd(base + G2 + 1,      w10 * fz);
    atomicAdd(base + G2 + GS,     w11 * (1.0f - fz));
    atomicAdd(base + G2 + GS + 1, w11 * fz);
}

extern "C" void kernel_launch(void* const* d_in, const int* in_sizes, int n_in,
                              void* d_out, int out_size, void* d_ws, size_t ws_size,
                              hipStream_t stream) {
    const float* pt  = (const float*)d_in[0];
    float*       out = (float*)d_out;

    const int P = in_sizes[0] / 3;       // total points (B*N)
    const int B = out_size / G3;         // 32
    const int N = (B > 0) ? P / B : 0;   // 262144

    const bool fast = (B > 0) && (out_size == B * G3) && (P == B * N) &&
                      (N % (4 * TPB) == 0);

    if (fast) {
        dim3 g(B, NSLAB);                // 256 wgs = 1/CU, one round
        gridding_u16_kernel<<<g, TPB, 0, stream>>>(pt, out, N);
    } else {
        hipMemsetAsync(d_out, 0, (size_t)out_size * sizeof(float), stream);
        gridding_atomic_kernel<<<(P + 255) / 256, 256, 0, stream>>>(pt, out, P, N);
    }
}